// Round 15
// baseline (183.258 us; speedup 1.0000x reference)
//
#include <hip/hip_runtime.h>
#include <cstddef>

// Problem constants
constexpr int kB   = 2;
constexpr int kS   = 2048;
constexpr int kHID = 2048;
constexpr int kH   = 16;
constexpr int kHKV = 4;
constexpr int kD   = 128;
constexpr int kL   = 64;
constexpr int kTok = kB * kS;             // 4096 tokens
constexpr int kNQKV = kH * kD + 2 * kHKV * kD;  // 3072 fused QKV cols

typedef __attribute__((ext_vector_type(8))) short bf16x8;
typedef __attribute__((ext_vector_type(4))) float f32x4;

static __device__ __forceinline__ short f2bf(float f) {
  union { float f; unsigned u; } v{f};
  const unsigned r = (v.u + 0x7fff + ((v.u >> 16) & 1)) >> 16;
  return (short)r;
}
static __device__ __forceinline__ float bf2f(short s) {
  union { unsigned u; float f; } v;
  v.u = ((unsigned)(unsigned short)s) << 16;
  return v.f;
}

static __device__ __forceinline__ bf16x8 pack8(float4 a, float4 b) {
  bf16x8 r;
  r[0] = f2bf(a.x); r[1] = f2bf(a.y); r[2] = f2bf(a.z); r[3] = f2bf(a.w);
  r[4] = f2bf(b.x); r[5] = f2bf(b.y); r[6] = f2bf(b.z); r[7] = f2bf(b.w);
  return r;
}

// packed fp32x2 -> bf16x2 (exact RTN) — no builtin on gfx950, inline asm
static __device__ __forceinline__ unsigned cvt_pk_bf16(float lo, float hi) {
  unsigned r;
  asm("v_cvt_pk_bf16_f32 %0, %1, %2" : "=v"(r) : "v"(lo), "v"(hi));
  return r;
}

// async global->LDS, 16B per lane. LDS dest must be wave-uniform base + lane*16.
typedef __attribute__((address_space(3))) void       lds_void;
typedef __attribute__((address_space(1))) const void gm_void;
static __device__ __forceinline__ void gload16(const void* g, void* l) {
  __builtin_amdgcn_global_load_lds((gm_void*)g, (lds_void*)l, 16, 0, 0);
}

// T1: bijective XCD-aware block swizzle (requires nwg % 8 == 0)
static __device__ __forceinline__ int2 xcd_swz(int nx, int ny) {
  int wg = blockIdx.y * nx + blockIdx.x;
  const int cpx = (nx * ny) >> 3;
  wg = (wg & 7) * cpx + (wg >> 3);
  int2 r; r.x = wg % nx; r.y = wg / nx;
  return r;
}

// ---------------------------------------------------------------------------
// Fused prep: one dispatch replacing 5 small kernels (block-uniform branches)
// ---------------------------------------------------------------------------
__global__ __launch_bounds__(256) void prep_all(
    const float* __restrict__ x, const int* __restrict__ pos,
    const float* __restrict__ Wq, const float* __restrict__ Wk,
    const float* __restrict__ Wv, const float* __restrict__ Wo,
    const float* __restrict__ Wql, const float* __restrict__ Wkl,
    const float* __restrict__ Wvl, short* __restrict__ x_bf,
    float* __restrict__ tbl, short* __restrict__ Wqkv,
    short* __restrict__ WoT, short* __restrict__ WqlT,
    short* __restrict__ WklT, short* __restrict__ WvlT) {
  __shared__ float T[64][65];
  const int bidg = blockIdx.x;
  const int tid = threadIdx.x;

  if (bidg < 4096) {                       // A: x -> bf16
    const int i = bidg * 256 + tid;
    const float4 a = *(const float4*)&x[(size_t)i * 8];
    const float4 b = *(const float4*)&x[(size_t)i * 8 + 4];
    *(bf16x8*)&x_bf[(size_t)i * 8] = pack8(a, b);
    return;
  }
  if (bidg < 5120) {                       // B: trig table
    const int idx = (bidg - 4096) * 256 + tid;
    const int i = idx & 63, t = idx >> 6;
    const float p = (float)pos[t];
    const float inv_freq = expf(-(float)i * (9.210340371976184f / 64.0f));
    const float ang = p * inv_freq;
    tbl[t * 128 + i]      = cosf(ang);
    tbl[t * 128 + 64 + i] = sinf(ang);
    return;
  }
  const int rr = tid >> 4, cc = tid & 15;
  if (bidg < 6656) {                       // C: QKV weight transpose
    const int idx = bidg - 5120;
    const int n0 = (idx % 48) * 64, k0 = (idx / 48) * 64;
    const float* in; int Nin, nl0;
    if (n0 < 2048)      { in = Wq; Nin = 2048; nl0 = n0; }
    else if (n0 < 2560) { in = Wk; Nin = 512;  nl0 = n0 - 2048; }
    else                { in = Wv; Nin = 512;  nl0 = n0 - 2560; }
#pragma unroll
    for (int ii = 0; ii < 4; ++ii) {
      const int kr = rr + ii * 16;
      const float4 v = *(const float4*)&in[(size_t)(k0 + kr) * Nin + nl0 + cc * 4];
      T[kr][cc * 4 + 0] = v.x; T[kr][cc * 4 + 1] = v.y;
      T[kr][cc * 4 + 2] = v.z; T[kr][cc * 4 + 3] = v.w;
    }
    __syncthreads();
#pragma unroll
    for (int ii = 0; ii < 4; ++ii) {
      const int n = rr + ii * 16;
      const short4 s4 = make_short4(f2bf(T[cc*4+0][n]), f2bf(T[cc*4+1][n]),
                                    f2bf(T[cc*4+2][n]), f2bf(T[cc*4+3][n]));
      *(short4*)&Wqkv[(size_t)(n0 + n) * kHID + k0 + cc * 4] = s4;
    }
    return;
  }
  if (bidg < 7168) {                       // D: Wo transpose (pad remap)
    const int idx = bidg - 6656;
    const int n0 = (idx % 32) * 64, k0 = (idx / 32) * 64;
#pragma unroll
    for (int ii = 0; ii < 4; ++ii) {
      const int kr = rr + ii * 16;
      const int gr = (((k0 + kr) >> 6) << 7) + ((k0 + kr) & 63);
      const float4 v = *(const float4*)&Wo[(size_t)gr * kHID + n0 + cc * 4];
      T[kr][cc * 4 + 0] = v.x; T[kr][cc * 4 + 1] = v.y;
      T[kr][cc * 4 + 2] = v.z; T[kr][cc * 4 + 3] = v.w;
    }
    __syncthreads();
#pragma unroll
    for (int ii = 0; ii < 4; ++ii) {
      const int n = rr + ii * 16;
      const short4 s4 = make_short4(f2bf(T[cc*4+0][n]), f2bf(T[cc*4+1][n]),
                                    f2bf(T[cc*4+2][n]), f2bf(T[cc*4+3][n]));
      *(short4*)&WoT[(size_t)(n0 + n) * (kH * kL) + k0 + cc * 4] = s4;
    }
    return;
  }
  {                                        // E: latent weight transposes
    const int idx = bidg - 7168;
    const int k0 = (idx & 1) * 64;
    const int z = idx >> 1;
    const float* in; short* out; float scale;
    if (z == 0)      { in = Wql; out = WqlT; scale = 0.125f; }
    else if (z == 1) { in = Wkl; out = WklT; scale = 1.0f; }
    else             { in = Wvl; out = WvlT; scale = 1.0f; }
#pragma unroll
    for (int ii = 0; ii < 4; ++ii) {
      const int kr = rr + ii * 16;
      const float4 v = *(const float4*)&in[(size_t)(k0 + kr) * kL + cc * 4];
      T[kr][cc * 4 + 0] = v.x * scale; T[kr][cc * 4 + 1] = v.y * scale;
      T[kr][cc * 4 + 2] = v.z * scale; T[kr][cc * 4 + 3] = v.w * scale;
    }
    __syncthreads();
#pragma unroll
    for (int ii = 0; ii < 4; ++ii) {
      const int n = rr + ii * 16;
      const short4 s4 = make_short4(f2bf(T[cc*4+0][n]), f2bf(T[cc*4+1][n]),
                                    f2bf(T[cc*4+2][n]), f2bf(T[cc*4+3][n]));
      *(short4*)&out[(size_t)n * kD + k0 + cc * 4] = s4;
    }
  }
}

// ---------------------------------------------------------------------------
// 256x256 2-deep pipelined bf16 MFMA GEMM for QKV (R10 structure, parked).
// ---------------------------------------------------------------------------
__global__ __launch_bounds__(512) void gemm_qkv8(
    const short* __restrict__ A, const short* __restrict__ Bt,
    short* __restrict__ C0, short* __restrict__ C1, short* __restrict__ C2,
    int K) {
  __shared__ short As[2][256 * 64];
  __shared__ short Bs[2][256 * 64];
  const int tid = threadIdx.x;
  const int lane = tid & 63, w = tid >> 6;
  const int lr = lane & 15, lk = lane >> 4;
  const int wm = w >> 2, wn = w & 3;
  const int2 sw = xcd_swz(kNQKV / 256, kTok / 256);   // 12 x 16 = 192 blocks
  const int row0 = sw.y * 256, col0 = sw.x * 256;
  const int NT = K >> 6;                               // 32

  auto stage = [&](int kt) {
    const int b = kt & 1;
    const int k0 = kt << 6;
#pragma unroll
    for (int j = 0; j < 4; ++j) {
      const int idx = j * 512 + tid;
      const int row = idx >> 3, blk = idx & 7;
      const int gcol = k0 + ((blk ^ (row & 7)) << 3);
      gload16(A + (size_t)(row0 + row) * K + gcol, &As[b][row * 64 + blk * 8]);
    }
#pragma unroll
    for (int j = 0; j < 4; ++j) {
      const int idx = j * 512 + tid;
      const int row = idx >> 3, blk = idx & 7;
      const int gcol = k0 + ((blk ^ (row & 7)) << 3);
      gload16(Bt + (size_t)(col0 + row) * K + gcol, &Bs[b][row * 64 + blk * 8]);
    }
  };

  f32x4 acc[8][4] = {};

  stage(0);
  for (int t = 0; t < NT; ++t) {
    const int b = t & 1;
    if (t + 1 < NT) {
      stage(t + 1);                                     // 2-deep prefetch
      asm volatile("s_waitcnt vmcnt(8)" ::: "memory");  // tile t drained
    } else {
      asm volatile("s_waitcnt vmcnt(0)" ::: "memory");
    }
    __builtin_amdgcn_s_barrier();                       // collective ready

    bf16x8 bb[4][2];
#pragma unroll
    for (int n = 0; n < 4; ++n) {
      const int row = wn * 64 + n * 16 + lr;
#pragma unroll
      for (int ch = 0; ch < 2; ++ch) {
        const int blk = (ch * 4 + lk) ^ (row & 7);
        bb[n][ch] = *(const bf16x8*)&Bs[b][row * 64 + blk * 8];
      }
    }
#pragma unroll
    for (int qm = 0; qm < 2; ++qm) {
      bf16x8 a[4][2];
#pragma unroll
      for (int j = 0; j < 4; ++j) {
        const int row = wm * 128 + (qm * 4 + j) * 16 + lr;
#pragma unroll
        for (int ch = 0; ch < 2; ++ch) {
          const int blk = (ch * 4 + lk) ^ (row & 7);
          a[j][ch] = *(const bf16x8*)&As[b][row * 64 + blk * 8];
        }
      }
      __builtin_amdgcn_s_setprio(1);
#pragma unroll
      for (int j = 0; j < 4; ++j)
#pragma unroll
        for (int n = 0; n < 4; ++n)
#pragma unroll
          for (int ch = 0; ch < 2; ++ch)
            acc[qm * 4 + j][n] = __builtin_amdgcn_mfma_f32_16x16x32_bf16(
                a[j][ch], bb[n][ch], acc[qm * 4 + j][n], 0, 0, 0);
      __builtin_amdgcn_s_setprio(0);
    }
    __builtin_amdgcn_s_barrier();
  }

  short* dst; int ld, cb;
  if (col0 < 2048)      { dst = C0; ld = 2048; cb = col0; }
  else if (col0 < 2560) { dst = C1; ld = 512;  cb = col0 - 2048; }
  else                  { dst = C2; ld = 512;  cb = col0 - 2560; }
  const int crow0 = row0 + wm * 128 + lk * 4;
  const int ccol0 = cb + wn * 64 + lr;
#pragma unroll
  for (int mf = 0; mf < 8; ++mf)
#pragma unroll
    for (int nf = 0; nf < 4; ++nf)
#pragma unroll
      for (int r = 0; r < 4; ++r)
        dst[(size_t)(crow0 + mf * 16 + r) * ld + ccol0 + nf * 16] =
            f2bf(acc[mf][nf][r]);
}

// ---------------------------------------------------------------------------
// 256(M)x128(N) 2-deep pipelined bf16 MFMA GEMM for the output projection.
// ---------------------------------------------------------------------------
__global__ __launch_bounds__(512) void gemm_out8(
    const short* __restrict__ A, const short* __restrict__ Bt,
    float* __restrict__ C, int M, int N, int K) {
  __shared__ short As[2][256 * 64];
  __shared__ short Bs[2][128 * 64];
  const int tid = threadIdx.x;
  const int lane = tid & 63, w = tid >> 6;
  const int lr = lane & 15, lk = lane >> 4;
  const int wm = w >> 2, wn = w & 3;
  const int2 sw = xcd_swz(N / 128, M / 256);          // 16 x 16 = 256 blocks
  const int row0 = sw.y * 256, col0 = sw.x * 128;
  const int NT = K >> 6;                               // 16

  auto stage = [&](int kt) {
    const int b = kt & 1;
    const int k0 = kt << 6;
#pragma unroll
    for (int j = 0; j < 4; ++j) {
      const int idx = j * 512 + tid;
      const int row = idx >> 3, blk = idx & 7;
      const int gcol = k0 + ((blk ^ (row & 7)) << 3);
      gload16(A + (size_t)(row0 + row) * K + gcol, &As[b][row * 64 + blk * 8]);
    }
#pragma unroll
    for (int j = 0; j < 2; ++j) {
      const int idx = j * 512 + tid;
      const int row = idx >> 3, blk = idx & 7;
      const int gcol = k0 + ((blk ^ (row & 7)) << 3);
      gload16(Bt + (size_t)(col0 + row) * K + gcol, &Bs[b][row * 64 + blk * 8]);
    }
  };

  f32x4 acc[8][2] = {};

  stage(0);
  for (int t = 0; t < NT; ++t) {
    const int b = t & 1;
    if (t + 1 < NT) {
      stage(t + 1);
      asm volatile("s_waitcnt vmcnt(6)" ::: "memory");
    } else {
      asm volatile("s_waitcnt vmcnt(0)" ::: "memory");
    }
    __builtin_amdgcn_s_barrier();

    bf16x8 bb[2][2];
#pragma unroll
    for (int n = 0; n < 2; ++n) {
      const int row = wn * 32 + n * 16 + lr;
#pragma unroll
      for (int ch = 0; ch < 2; ++ch) {
        const int blk = (ch * 4 + lk) ^ (row & 7);
        bb[n][ch] = *(const bf16x8*)&Bs[b][row * 64 + blk * 8];
      }
    }
#pragma unroll
    for (int qm = 0; qm < 2; ++qm) {
      bf16x8 a[4][2];
#pragma unroll
      for (int j = 0; j < 4; ++j) {
        const int row = wm * 128 + (qm * 4 + j) * 16 + lr;
#pragma unroll
        for (int ch = 0; ch < 2; ++ch) {
          const int blk = (ch * 4 + lk) ^ (row & 7);
          a[j][ch] = *(const bf16x8*)&As[b][row * 64 + blk * 8];
        }
      }
      __builtin_amdgcn_s_setprio(1);
#pragma unroll
      for (int j = 0; j < 4; ++j)
#pragma unroll
        for (int n = 0; n < 2; ++n)
#pragma unroll
          for (int ch = 0; ch < 2; ++ch)
            acc[qm * 4 + j][n] = __builtin_amdgcn_mfma_f32_16x16x32_bf16(
                a[j][ch], bb[n][ch], acc[qm * 4 + j][n], 0, 0, 0);
      __builtin_amdgcn_s_setprio(0);
    }
    __builtin_amdgcn_s_barrier();
  }

  const int crow0 = row0 + wm * 128 + lk * 4;
  const int ccol0 = col0 + wn * 32 + lr;
#pragma unroll
  for (int mf = 0; mf < 8; ++mf)
#pragma unroll
    for (int nf = 0; nf < 2; ++nf)
#pragma unroll
      for (int r = 0; r < 4; ++r)
        C[(size_t)(crow0 + mf * 16 + r) * N + ccol0 + nf * 16] = acc[mf][nf][r];
}

// ---------------------------------------------------------------------------
// Fused RoPE + latent projection (MFMA), bf16 input, all three tensors in
// one dispatch. grid = (kS/64, 48). Branches block-uniform.
// ---------------------------------------------------------------------------
__global__ __launch_bounds__(256) void rope_latent_all(
    const short* __restrict__ qb, const short* __restrict__ kb,
    const short* __restrict__ vb, const short* __restrict__ WqlT,
    const short* __restrict__ WklT, const short* __restrict__ WvlT,
    const float* __restrict__ tbl, short* __restrict__ q_l,
    short* __restrict__ k_l, short* __restrict__ v_lT) {
  __shared__ short Tw[4][1280];
  const int yz = blockIdx.y;
  const short* in; const short* WT; short* out; int nh; bool ROPE, TR;
  int bh;
  if (yz < 32)      { in = qb; WT = WqlT; out = q_l;  nh = kH;   ROPE = true;  TR = false; bh = yz; }
  else if (yz < 40) { in = kb; WT = WklT; out = k_l;  nh = kHKV; ROPE = true;  TR = false; bh = yz - 32; }
  else              { in = vb; WT = WvlT; out = v_lT; nh = kHKV; ROPE = false; TR = true;  bh = yz - 40; }

  const int tid = threadIdx.x;
  const int lane = tid & 63;
  const int w = tid >> 6;
  const int lr = lane & 15;
  const int lk = lane >> 4;
  const int b = bh / nh, h = bh % nh;
  const int s0 = blockIdx.x * 64;
  const int srow = s0 + w * 16 + lr;
  const int tok = b * kS + srow;

  const short* ip = in + ((size_t)tok * nh + h) * kD + lk * 8;
  bf16x8 raw[4];
#pragma unroll
  for (int ch = 0; ch < 4; ++ch) raw[ch] = *(const bf16x8*)(ip + ch * 32);

  bf16x8 af[4];
  if (ROPE) {
    float a[4][8];
#pragma unroll
    for (int ch = 0; ch < 4; ++ch)
#pragma unroll
      for (int i = 0; i < 8; ++i) a[ch][i] = bf2f(raw[ch][i]);
    const float* tb = tbl + (size_t)tok * 128;
    float c[2][8], sn[2][8];
#pragma unroll
    for (int g = 0; g < 2; ++g) {
      const float4 cA = *(const float4*)(tb + g * 32 + lk * 8);
      const float4 cB = *(const float4*)(tb + g * 32 + lk * 8 + 4);
      const float4 sA = *(const float4*)(tb + 64 + g * 32 + lk * 8);
      const float4 sB = *(const float4*)(tb + 64 + g * 32 + lk * 8 + 4);
      c[g][0] = cA.x; c[g][1] = cA.y; c[g][2] = cA.z; c[g][3] = cA.w;
      c[g][4] = cB.x; c[g][5] = cB.y; c[g][6] = cB.z; c[g][7] = cB.w;
      sn[g][0] = sA.x; sn[g][1] = sA.y; sn[g][2] = sA.z; sn[g][3] = sA.w;
      sn[g][4] = sB.x; sn[g][5] = sB.y; sn[g][6] = sB.z; sn[g][7] = sB.w;
    }
    float o[4][8];
#pragma unroll
    for (int g = 0; g < 2; ++g)
#pragma unroll
      for (int i = 0; i < 8; ++i) {
        o[g][i]     = a[g][i]     * c[g][i] - a[g + 2][i] * sn[g][i];
        o[g + 2][i] = a[g + 2][i] * c[g][i] + a[g][i]     * sn[g][i];
      }
#pragma unroll
    for (int ch = 0; ch < 4; ++ch)
#pragma unroll
      for (int i = 0; i < 8; ++i) af[ch][i] = f2bf(o[ch][i]);
  } else {
#pragma unroll
    for (int ch = 0; ch < 4; ++ch) af[ch] = raw[ch];
  }

  f32x4 acc[4] = {};
#pragma unroll
  for (int cb = 0; cb < 4; ++cb) {
#pragma unroll
    for (int ch = 0; ch < 4; ++ch) {
      const bf16x8 bfrag =
          *(const bf16x8*)&WT[(size_t)(cb * 16 + lr) * kD + ch * 32 + lk * 8];
      acc[cb] = __builtin_amdgcn_mfma_f32_16x16x32_bf16(af[ch], bfrag,
                                                        acc[cb], 0, 0, 0);
    }
  }

  short* T = Tw[w];
  if (!TR) {
#pragma unroll
    for (int cb = 0; cb < 4; ++cb)
#pragma unroll
      for (int r = 0; r < 4; ++r)
        T[(lk * 4 + r) * 72 + cb * 16 + lr] = f2bf(acc[cb][r]);
    asm volatile("s_waitcnt lgkmcnt(0)" ::: "memory");
#pragma unroll
    for (int it = 0; it < 2; ++it) {
      const int idx = it * 64 + lane;
      const int row = idx >> 3, c8 = (idx & 7) << 3;
      *(bf16x8*)&out[((size_t)bh * kS + s0 + w * 16 + row) * kL + c8] =
          *(const bf16x8*)&T[row * 72 + c8];
    }
  } else {
#pragma unroll
    for (int cb = 0; cb < 4; ++cb)
#pragma unroll
      for (int r = 0; r < 4; ++r)
        T[(cb * 16 + lr) * 20 + lk * 4 + r] = f2bf(acc[cb][r]);
    asm volatile("s_waitcnt lgkmcnt(0)" ::: "memory");
    const size_t orow = ((size_t)bh * kL + lane) * kS + s0 + w * 16;
#pragma unroll
    for (int c = 0; c < 4; ++c)
      *(short4*)&out[orow + c * 4] = *(const short4*)&T[lane * 20 + c * 4];
  }
}

// ---------------------------------------------------------------------------
// MFMA flash attention, causal, bf16 in/out (fp32 accumulate).
// Swapped QK^T (q lane-local), in-register P via shuffles, T13 defer-max.
// TWO q-tiles per block (bx and its causal complement 15-bx): per-CU compute
// constant (17 units) AND 26% less K/V staging; each staged 128-key tile
// serves both q-tiles where causally active. grid (B*H, 8) = 256 blocks.
// ---------------------------------------------------------------------------
__global__ __launch_bounds__(512) void flash_attn_mfma(
    const short* __restrict__ ql, const short* __restrict__ kl,
    const short* __restrict__ vlT, short* __restrict__ attn_out) {
  constexpr int LDK = 72;                      // K rows: 64 lat + 8 pad
  constexpr int LDV = 136;                     // V rows: 128 keys + 8 pad
  __shared__ short Kt[2][128 * LDK];
  __shared__ short Vt[2][64 * LDV];            // row = latent l, col = key

  const int tid = threadIdx.x;
  const int lane = tid & 63;
  const int w = tid >> 6;
  const int lr = lane & 15;
  const int lk = lane >> 4;
  const int bxA = blockIdx.y;                  // light q-tile (0..7)
  const int bxB = 15 - bxA;                    // heavy complement
  const int bh = blockIdx.x;
  const int b = bh >> 4, h = bh & 15;
  const int hk = h >> 2;
  const int wrowA = bxA * 128 + w * 16;
  const int wrowB = bxB * 128 + w * 16;

  const short* qbase = ql + (size_t)bh * kS * kL;
  bf16x8 qfA[2], qfB[2];
  qfA[0] = *(const bf16x8*)(qbase + (size_t)(wrowA + lr) * kL + lk * 8);
  qfA[1] = *(const bf16x8*)(qbase + (size_t)(wrowA + lr) * kL + 32 + lk * 8);
  qfB[0] = *(const bf16x8*)(qbase + (size_t)(wrowB + lr) * kL + lk * 8);
  qfB[1] = *(const bf16x8*)(qbase + (size_t)(wrowB + lr) * kL + 32 + lk * 8);

  f32x4 OfA[4] = {}, OfB[4] = {};              // O^T[l=lb*16+lk*4+r][q=lr]
  float mA = -3.0e38f, lA = 0.f, mB = -3.0e38f, lB = 0.f;

  const short* kgp = kl + (size_t)(b * kHKV + hk) * kS * kL;
  const short* vgp = vlT + (size_t)(b * kHKV + hk) * kL * kS;
  const int ntiles = bxB + 1;                  // staged 128-key tiles

  const int kr0 = tid >> 3,          kc0 = (tid & 7) << 3;
  const int kr1 = (512 + tid) >> 3,  kc1 = (tid & 7) << 3;
  const int vr0 = tid >> 4,          vc0 = (tid & 15) << 3;
  const int vr1 = (512 + tid) >> 4,  vc1 = (tid & 15) << 3;

  // prologue: stage tile 0 (keys 0..127) into buffer 0
  *(bf16x8*)&Kt[0][kr0 * LDK + kc0] = *(const bf16x8*)(kgp + (size_t)kr0 * kL + kc0);
  *(bf16x8*)&Kt[0][kr1 * LDK + kc1] = *(const bf16x8*)(kgp + (size_t)kr1 * kL + kc1);
  *(bf16x8*)&Vt[0][vr0 * LDV + vc0] = *(const bf16x8*)(vgp + (size_t)vr0 * kS + vc0);
  *(bf16x8*)&Vt[0][vr1 * LDV + vc1] = *(const bf16x8*)(vgp + (size_t)vr1 * kS + vc1);
  __syncthreads();

  const int sl0 = lr + ((lane & 16) << 1);     // lr + 32*(lk&1)
  const bool hisel = (lk >> 1) != 0;

  // one 64-key subtile against one q-state (statically-named args -> inlined)
  auto proc = [&](const bf16x8 (&qf)[2], f32x4 (&Of)[4], float& m, float& l,
                  int wrow, int js, int sub, const short* Kc, const short* Vc) {
    f32x4 Sf[4];
    __builtin_amdgcn_s_setprio(1);
#pragma unroll
    for (int cb = 0; cb < 4; ++cb) {
      f32x4 acc = {};
#pragma unroll
      for (int ch = 0; ch < 2; ++ch) {
        const bf16x8 kf = *(const bf16x8*)
            &Kc[(sub * 64 + cb * 16 + lr) * LDK + ch * 32 + lk * 8];
        acc = __builtin_amdgcn_mfma_f32_16x16x32_bf16(kf, qf[ch], acc, 0, 0, 0);
      }
      Sf[cb] = acc;
    }
    __builtin_amdgcn_s_setprio(0);

    float mt = -3.0e38f;
    if (js + 63 > wrow) {                      // diagonal subtile: mask
#pragma unroll
      for (int cb = 0; cb < 4; ++cb)
#pragma unroll
        for (int r = 0; r < 4; ++r) {
          float s = Sf[cb][r];
          if ((js + cb * 16 + lk * 4 + r) > (wrow + lr)) s = -3.0e38f;
          Sf[cb][r] = s;
          mt = fmaxf(mt, s);
        }
    } else {
#pragma unroll
      for (int cb = 0; cb < 4; ++cb)
#pragma unroll
        for (int r = 0; r < 4; ++r) mt = fmaxf(mt, Sf[cb][r]);
    }
    mt = fmaxf(mt, __shfl_xor(mt, 16));
    mt = fmaxf(mt, __shfl_xor(mt, 32));

    const bool resc = __any((int)(mt > m + 8.f));   // T13 defer-max
    if (resc) {
      const float mnew = fmaxf(m, mt);
      const float corr = __expf(m - mnew);
      m = mnew;
      l *= corr;
#pragma unroll
      for (int lb = 0; lb < 4; ++lb)
#pragma unroll
        for (int r = 0; r < 4; ++r) Of[lb][r] *= corr;
    }

    unsigned pk[4][2];
#pragma unroll
    for (int cb = 0; cb < 4; ++cb) {
      const float p0 = __expf(Sf[cb][0] - m);
      const float p1 = __expf(Sf[cb][1] - m);
      const float p2 = __expf(Sf[cb][2] - m);
      const float p3 = __expf(Sf[cb][3] - m);
      l += (p0 + p1) + (p2 + p3);
      pk[cb][0] = cvt_pk_bf16(p0, p1);
      pk[cb][1] = cvt_pk_bf16(p2, p3);
    }

#pragma unroll
    for (int ch = 0; ch < 2; ++ch) {
      const unsigned lo00 = __shfl(pk[2 * ch][0], sl0);
      const unsigned lo01 = __shfl(pk[2 * ch][1], sl0);
      const unsigned lo10 = __shfl(pk[2 * ch][0], sl0 + 16);
      const unsigned lo11 = __shfl(pk[2 * ch][1], sl0 + 16);
      const unsigned hi00 = __shfl(pk[2 * ch + 1][0], sl0);
      const unsigned hi01 = __shfl(pk[2 * ch + 1][1], sl0);
      const unsigned hi10 = __shfl(pk[2 * ch + 1][0], sl0 + 16);
      const unsigned hi11 = __shfl(pk[2 * ch + 1][1], sl0 + 16);
      union { unsigned u[4]; bf16x8 v; } pf;
      pf.u[0] = hisel ? hi00 : lo00;
      pf.u[1] = hisel ? hi01 : lo01;
      pf.u[2] = hisel ? hi10 : lo10;
      pf.u[3] = hisel ? hi11 : lo11;
      __builtin_amdgcn_s_setprio(1);
#pragma unroll
      for (int lb = 0; lb < 4; ++lb) {
        const bf16x8 vf = *(const bf16x8*)
            &Vc[(lb * 16 + lr) * LDV + sub * 64 + ch * 32 + lk * 8];
        Of[lb] = __builtin_amdgcn_mfma_f32_16x16x32_bf16(vf, pf.v, Of[lb], 0, 0, 0);
      }
      __builtin_amdgcn_s_setprio(0);
    }
  };

  int cur = 0;
  for (int t = 0; t < ntiles; ++t) {
    const int j0 = t * 128;
    const bool pre = (t + 1 < ntiles);
    bf16x8 krn0, krn1, vrn0, vrn1;
    if (pre) {                                 // issue next-tile loads EARLY
      const int jn = j0 + 128;
      krn0 = *(const bf16x8*)(kgp + (size_t)(jn + kr0) * kL + kc0);
      krn1 = *(const bf16x8*)(kgp + (size_t)(jn + kr1) * kL + kc1);
      vrn0 = *(const bf16x8*)(vgp + (size_t)vr0 * kS + jn + vc0);
      vrn1 = *(const bf16x8*)(vgp + (size_t)vr1 * kS + jn + vc1);
    }

    const short* Kc = &Kt[cur][0];
    const short* Vc = &Vt[cur][0];
#pragma unroll
    for (int sub = 0; sub < 2; ++sub) {
      const int js = j0 + sub * 64;
      if (js <= wrowA) proc(qfA, OfA, mA, lA, wrowA, js, sub, Kc, Vc);
      if (js <= wrowB) proc(qfB, OfB, mB, lB, wrowB, js, sub, Kc, Vc);
    }

    if (pre) {                                 // write-late into other buffer
      *(bf16x8*)&Kt[cur ^ 1][kr0 * LDK + kc0] = krn0;
      *(bf16x8*)&Kt[cur ^ 1][kr1 * LDK + kc1] = krn1;
      *(bf16x8*)&Vt[cur ^ 1][vr0 * LDV + vc0] = vrn0;
      *(bf16x8*)&Vt[cur ^ 1][vr1 * LDV + vc1] = vrn1;
    }
    __syncthreads();                           // ONE barrier per 128 keys
    cur ^= 1;
  }

  // final lsum reduce + O^T writes (4x short4 per lane per q-tile)
  lA += __shfl_xor(lA, 16);  lA += __shfl_xor(lA, 32);
  lB += __shfl_xor(lB, 16);  lB += __shfl_xor(lB, 32);
  const float invA = 1.f / lA, invB = 1.f / lB;
  const size_t rowA =
      (size_t)(b * kS + wrowA + lr) * (kH * kL) + h * kL + lk * 4;
  const size_t rowB =
      (size_t)(b * kS + wrowB + lr) * (kH * kL) + h * kL + lk * 4;
#pragma unroll
  for (int lb = 0; lb < 4; ++lb) {
    const short4 sA = make_short4(f2bf(OfA[lb][0] * invA), f2bf(OfA[lb][1] * invA),
                                  f2bf(OfA[lb][2] * invA), f2bf(OfA[lb][3] * invA));
    *(short4*)&attn_out[rowA + lb * 16] = sA;
    const short4 sB = make_short4(f2bf(OfB[lb][0] * invB), f2bf(OfB[lb][1] * invB),
                                  f2bf(OfB[lb][2] * invB), f2bf(OfB[lb][3] * invB));
    *(short4*)&attn_out[rowB + lb * 16] = sB;
  }
}

// ---------------------------------------------------------------------------
extern "C" void kernel_launch(void* const* d_in, const int* in_sizes, int n_in,
                              void* d_out, int out_size, void* d_ws, size_t ws_size,
                              hipStream_t stream) {
  const float* x    = (const float*)d_in[0];
  const int*   pos  = (const int*)d_in[1];
  const float* Wq   = (const float*)d_in[3];
  const float* Wk   = (const float*)d_in[4];
  const float* Wv   = (const float*)d_in[5];
  const float* Wql  = (const float*)d_in[6];
  const float* Wkl  = (const float*)d_in[7];
  const float* Wvl  = (const float*)d_in[8];
  const float* Wo   = (const float*)d_in[9];
  float* out = (float*)d_out;

  // Workspace carve (q_buf bf16 reuses d_out: 16 MB of its 32 MB)
  char* p = (char*)d_ws;
  short* x_bf  = (short*)p; p += (size_t)kTok * kHID * 2;        // 16 MB
  short* Wqkv  = (short*)p; p += (size_t)kNQKV * kHID * 2;       // 12.6 MB
  short* WoT   = (short*)p; p += (size_t)kHID * (kH * kL) * 2;   // 4 MB
  short* WqlT  = (short*)p; p += (size_t)kL * kD * 2;            // 16 KB
  short* WklT  = (short*)p; p += (size_t)kL * kD * 2;
  short* WvlT  = (short*)p; p += (size_t)kL * kD * 2;
  float* tbl   = (float*)p; p += (size_t)kTok * 128 * 4;         // 2 MB
  short* k_buf = (short*)p; p += (size_t)kTok * kHKV * kD * 2;   // 4 MB
  short* v_buf = (short*)p; p += (size_t)kTok * kHKV * kD * 2;   // 4 MB
  short* q_l   = (short*)p; p += (size_t)kB * kH * kS * kL * 2;  // 8 MB
  short* k_l   = (short*)p; p += (size_t)kB * kHKV * kS * kL * 2;
  short* v_lT  = (short*)p; p += (size_t)kB * kHKV * kS * kL * 2;
  short* attn  = (short*)p;                                      // 8 MB
  short* q_buf = (short*)d_out;   // bf16 scratch until final GEMM

  // 0) fused prep — one dispatch (cvt + trig + 3 weight transposes)
  prep_all<<<7174, 256, 0, stream>>>(x, pos, Wq, Wk, Wv, Wo, Wql, Wkl, Wvl,
                                     x_bf, tbl, Wqkv, WoT, WqlT, WklT, WvlT);

  // 1) Fused QKV projection — 256² 2-deep counted-vmcnt, register-blocked
  gemm_qkv8<<<dim3(kNQKV / 256, kTok / 256), 512, 0, stream>>>(
      x_bf, Wqkv, q_buf, k_buf, v_buf, kHID);

  // 2) Fused RoPE + latent projections — single dispatch
  rope_latent_all<<<dim3(kS / 64, 48), 256, 0, stream>>>(
      q_buf, k_buf, v_buf, WqlT, WklT, WvlT, tbl, q_l, k_l, v_lT);

  // 3) MFMA flash attention (swapped QK^T, paired q-tiles, 128-key dbuf)
  flash_attn_mfma<<<dim3(kB * kH, 8), 512, 0, stream>>>(
      q_l, k_l, v_lT, attn);

  // 4) Output GEMM — 256x128 2-deep, 256 blocks = 1/CU, fp32 out
  gemm_out8<<<dim3(kHID / 128, kTok / 256), 512, 0, stream>>>(
      attn, WoT, out, kTok, kHID, kH * kL);
}

// Round 16
// 180.199 us; speedup vs baseline: 1.0170x; 1.0170x over previous
//
#include <hip/hip_runtime.h>
#include <cstddef>

// Problem constants
constexpr int kB   = 2;
constexpr int kS   = 2048;
constexpr int kHID = 2048;
constexpr int kH   = 16;
constexpr int kHKV = 4;
constexpr int kD   = 128;
constexpr int kL   = 64;
constexpr int kTok = kB * kS;             // 4096 tokens
constexpr int kNQKV = kH * kD + 2 * kHKV * kD;  // 3072 fused QKV cols

typedef __attribute__((ext_vector_type(8))) short bf16x8;
typedef __attribute__((ext_vector_type(4))) float f32x4;

static __device__ __forceinline__ short f2bf(float f) {
  union { float f; unsigned u; } v{f};
  const unsigned r = (v.u + 0x7fff + ((v.u >> 16) & 1)) >> 16;
  return (short)r;
}
static __device__ __forceinline__ float bf2f(short s) {
  union { unsigned u; float f; } v;
  v.u = ((unsigned)(unsigned short)s) << 16;
  return v.f;
}

static __device__ __forceinline__ bf16x8 pack8(float4 a, float4 b) {
  bf16x8 r;
  r[0] = f2bf(a.x); r[1] = f2bf(a.y); r[2] = f2bf(a.z); r[3] = f2bf(a.w);
  r[4] = f2bf(b.x); r[5] = f2bf(b.y); r[6] = f2bf(b.z); r[7] = f2bf(b.w);
  return r;
}

// packed fp32x2 -> bf16x2 (exact RTN) — no builtin on gfx950, inline asm
static __device__ __forceinline__ unsigned cvt_pk_bf16(float lo, float hi) {
  unsigned r;
  asm("v_cvt_pk_bf16_f32 %0, %1, %2" : "=v"(r) : "v"(lo), "v"(hi));
  return r;
}

// async global->LDS, 16B per lane. LDS dest must be wave-uniform base + lane*16.
typedef __attribute__((address_space(3))) void       lds_void;
typedef __attribute__((address_space(1))) const void gm_void;
static __device__ __forceinline__ void gload16(const void* g, void* l) {
  __builtin_amdgcn_global_load_lds((gm_void*)g, (lds_void*)l, 16, 0, 0);
}

// T1: bijective XCD-aware block swizzle (requires nwg % 8 == 0)
static __device__ __forceinline__ int2 xcd_swz(int nx, int ny) {
  int wg = blockIdx.y * nx + blockIdx.x;
  const int cpx = (nx * ny) >> 3;
  wg = (wg & 7) * cpx + (wg >> 3);
  int2 r; r.x = wg % nx; r.y = wg / nx;
  return r;
}

// ---------------------------------------------------------------------------
// Fused prep: one dispatch replacing 5 small kernels (block-uniform branches)
// ---------------------------------------------------------------------------
__global__ __launch_bounds__(256) void prep_all(
    const float* __restrict__ x, const int* __restrict__ pos,
    const float* __restrict__ Wq, const float* __restrict__ Wk,
    const float* __restrict__ Wv, const float* __restrict__ Wo,
    const float* __restrict__ Wql, const float* __restrict__ Wkl,
    const float* __restrict__ Wvl, short* __restrict__ x_bf,
    float* __restrict__ tbl, short* __restrict__ Wqkv,
    short* __restrict__ WoT, short* __restrict__ WqlT,
    short* __restrict__ WklT, short* __restrict__ WvlT) {
  __shared__ float T[64][65];
  const int bidg = blockIdx.x;
  const int tid = threadIdx.x;

  if (bidg < 4096) {                       // A: x -> bf16
    const int i = bidg * 256 + tid;
    const float4 a = *(const float4*)&x[(size_t)i * 8];
    const float4 b = *(const float4*)&x[(size_t)i * 8 + 4];
    *(bf16x8*)&x_bf[(size_t)i * 8] = pack8(a, b);
    return;
  }
  if (bidg < 5120) {                       // B: trig table
    const int idx = (bidg - 4096) * 256 + tid;
    const int i = idx & 63, t = idx >> 6;
    const float p = (float)pos[t];
    const float inv_freq = expf(-(float)i * (9.210340371976184f / 64.0f));
    const float ang = p * inv_freq;
    tbl[t * 128 + i]      = cosf(ang);
    tbl[t * 128 + 64 + i] = sinf(ang);
    return;
  }
  const int rr = tid >> 4, cc = tid & 15;
  if (bidg < 6656) {                       // C: QKV weight transpose
    const int idx = bidg - 5120;
    const int n0 = (idx % 48) * 64, k0 = (idx / 48) * 64;
    const float* in; int Nin, nl0;
    if (n0 < 2048)      { in = Wq; Nin = 2048; nl0 = n0; }
    else if (n0 < 2560) { in = Wk; Nin = 512;  nl0 = n0 - 2048; }
    else                { in = Wv; Nin = 512;  nl0 = n0 - 2560; }
#pragma unroll
    for (int ii = 0; ii < 4; ++ii) {
      const int kr = rr + ii * 16;
      const float4 v = *(const float4*)&in[(size_t)(k0 + kr) * Nin + nl0 + cc * 4];
      T[kr][cc * 4 + 0] = v.x; T[kr][cc * 4 + 1] = v.y;
      T[kr][cc * 4 + 2] = v.z; T[kr][cc * 4 + 3] = v.w;
    }
    __syncthreads();
#pragma unroll
    for (int ii = 0; ii < 4; ++ii) {
      const int n = rr + ii * 16;
      const short4 s4 = make_short4(f2bf(T[cc*4+0][n]), f2bf(T[cc*4+1][n]),
                                    f2bf(T[cc*4+2][n]), f2bf(T[cc*4+3][n]));
      *(short4*)&Wqkv[(size_t)(n0 + n) * kHID + k0 + cc * 4] = s4;
    }
    return;
  }
  if (bidg < 7168) {                       // D: Wo transpose (pad remap)
    const int idx = bidg - 6656;
    const int n0 = (idx % 32) * 64, k0 = (idx / 32) * 64;
#pragma unroll
    for (int ii = 0; ii < 4; ++ii) {
      const int kr = rr + ii * 16;
      const int gr = (((k0 + kr) >> 6) << 7) + ((k0 + kr) & 63);
      const float4 v = *(const float4*)&Wo[(size_t)gr * kHID + n0 + cc * 4];
      T[kr][cc * 4 + 0] = v.x; T[kr][cc * 4 + 1] = v.y;
      T[kr][cc * 4 + 2] = v.z; T[kr][cc * 4 + 3] = v.w;
    }
    __syncthreads();
#pragma unroll
    for (int ii = 0; ii < 4; ++ii) {
      const int n = rr + ii * 16;
      const short4 s4 = make_short4(f2bf(T[cc*4+0][n]), f2bf(T[cc*4+1][n]),
                                    f2bf(T[cc*4+2][n]), f2bf(T[cc*4+3][n]));
      *(short4*)&WoT[(size_t)(n0 + n) * (kH * kL) + k0 + cc * 4] = s4;
    }
    return;
  }
  {                                        // E: latent weight transposes
    const int idx = bidg - 7168;
    const int k0 = (idx & 1) * 64;
    const int z = idx >> 1;
    const float* in; short* out; float scale;
    if (z == 0)      { in = Wql; out = WqlT; scale = 0.125f; }
    else if (z == 1) { in = Wkl; out = WklT; scale = 1.0f; }
    else             { in = Wvl; out = WvlT; scale = 1.0f; }
#pragma unroll
    for (int ii = 0; ii < 4; ++ii) {
      const int kr = rr + ii * 16;
      const float4 v = *(const float4*)&in[(size_t)(k0 + kr) * kL + cc * 4];
      T[kr][cc * 4 + 0] = v.x * scale; T[kr][cc * 4 + 1] = v.y * scale;
      T[kr][cc * 4 + 2] = v.z * scale; T[kr][cc * 4 + 3] = v.w * scale;
    }
    __syncthreads();
#pragma unroll
    for (int ii = 0; ii < 4; ++ii) {
      const int n = rr + ii * 16;
      const short4 s4 = make_short4(f2bf(T[cc*4+0][n]), f2bf(T[cc*4+1][n]),
                                    f2bf(T[cc*4+2][n]), f2bf(T[cc*4+3][n]));
      *(short4*)&out[(size_t)n * kD + k0 + cc * 4] = s4;
    }
  }
}

// ---------------------------------------------------------------------------
// 256x256 2-deep pipelined bf16 MFMA GEMM for QKV (R10 structure, parked).
// ---------------------------------------------------------------------------
__global__ __launch_bounds__(512) void gemm_qkv8(
    const short* __restrict__ A, const short* __restrict__ Bt,
    short* __restrict__ C0, short* __restrict__ C1, short* __restrict__ C2,
    int K) {
  __shared__ short As[2][256 * 64];
  __shared__ short Bs[2][256 * 64];
  const int tid = threadIdx.x;
  const int lane = tid & 63, w = tid >> 6;
  const int lr = lane & 15, lk = lane >> 4;
  const int wm = w >> 2, wn = w & 3;
  const int2 sw = xcd_swz(kNQKV / 256, kTok / 256);   // 12 x 16 = 192 blocks
  const int row0 = sw.y * 256, col0 = sw.x * 256;
  const int NT = K >> 6;                               // 32

  auto stage = [&](int kt) {
    const int b = kt & 1;
    const int k0 = kt << 6;
#pragma unroll
    for (int j = 0; j < 4; ++j) {
      const int idx = j * 512 + tid;
      const int row = idx >> 3, blk = idx & 7;
      const int gcol = k0 + ((blk ^ (row & 7)) << 3);
      gload16(A + (size_t)(row0 + row) * K + gcol, &As[b][row * 64 + blk * 8]);
    }
#pragma unroll
    for (int j = 0; j < 4; ++j) {
      const int idx = j * 512 + tid;
      const int row = idx >> 3, blk = idx & 7;
      const int gcol = k0 + ((blk ^ (row & 7)) << 3);
      gload16(Bt + (size_t)(col0 + row) * K + gcol, &Bs[b][row * 64 + blk * 8]);
    }
  };

  f32x4 acc[8][4] = {};

  stage(0);
  for (int t = 0; t < NT; ++t) {
    const int b = t & 1;
    if (t + 1 < NT) {
      stage(t + 1);                                     // 2-deep prefetch
      asm volatile("s_waitcnt vmcnt(8)" ::: "memory");  // tile t drained
    } else {
      asm volatile("s_waitcnt vmcnt(0)" ::: "memory");
    }
    __builtin_amdgcn_s_barrier();                       // collective ready

    bf16x8 bb[4][2];
#pragma unroll
    for (int n = 0; n < 4; ++n) {
      const int row = wn * 64 + n * 16 + lr;
#pragma unroll
      for (int ch = 0; ch < 2; ++ch) {
        const int blk = (ch * 4 + lk) ^ (row & 7);
        bb[n][ch] = *(const bf16x8*)&Bs[b][row * 64 + blk * 8];
      }
    }
#pragma unroll
    for (int qm = 0; qm < 2; ++qm) {
      bf16x8 a[4][2];
#pragma unroll
      for (int j = 0; j < 4; ++j) {
        const int row = wm * 128 + (qm * 4 + j) * 16 + lr;
#pragma unroll
        for (int ch = 0; ch < 2; ++ch) {
          const int blk = (ch * 4 + lk) ^ (row & 7);
          a[j][ch] = *(const bf16x8*)&As[b][row * 64 + blk * 8];
        }
      }
      __builtin_amdgcn_s_setprio(1);
#pragma unroll
      for (int j = 0; j < 4; ++j)
#pragma unroll
        for (int n = 0; n < 4; ++n)
#pragma unroll
          for (int ch = 0; ch < 2; ++ch)
            acc[qm * 4 + j][n] = __builtin_amdgcn_mfma_f32_16x16x32_bf16(
                a[j][ch], bb[n][ch], acc[qm * 4 + j][n], 0, 0, 0);
      __builtin_amdgcn_s_setprio(0);
    }
    __builtin_amdgcn_s_barrier();
  }

  short* dst; int ld, cb;
  if (col0 < 2048)      { dst = C0; ld = 2048; cb = col0; }
  else if (col0 < 2560) { dst = C1; ld = 512;  cb = col0 - 2048; }
  else                  { dst = C2; ld = 512;  cb = col0 - 2560; }
  const int crow0 = row0 + wm * 128 + lk * 4;
  const int ccol0 = cb + wn * 64 + lr;
#pragma unroll
  for (int mf = 0; mf < 8; ++mf)
#pragma unroll
    for (int nf = 0; nf < 4; ++nf)
#pragma unroll
      for (int r = 0; r < 4; ++r)
        dst[(size_t)(crow0 + mf * 16 + r) * ld + ccol0 + nf * 16] =
            f2bf(acc[mf][nf][r]);
}

// ---------------------------------------------------------------------------
// 256(M)x128(N) 2-deep pipelined bf16 MFMA GEMM for the output projection.
// ---------------------------------------------------------------------------
__global__ __launch_bounds__(512) void gemm_out8(
    const short* __restrict__ A, const short* __restrict__ Bt,
    float* __restrict__ C, int M, int N, int K) {
  __shared__ short As[2][256 * 64];
  __shared__ short Bs[2][128 * 64];
  const int tid = threadIdx.x;
  const int lane = tid & 63, w = tid >> 6;
  const int lr = lane & 15, lk = lane >> 4;
  const int wm = w >> 2, wn = w & 3;
  const int2 sw = xcd_swz(N / 128, M / 256);          // 16 x 16 = 256 blocks
  const int row0 = sw.y * 256, col0 = sw.x * 128;
  const int NT = K >> 6;                               // 16

  auto stage = [&](int kt) {
    const int b = kt & 1;
    const int k0 = kt << 6;
#pragma unroll
    for (int j = 0; j < 4; ++j) {
      const int idx = j * 512 + tid;
      const int row = idx >> 3, blk = idx & 7;
      const int gcol = k0 + ((blk ^ (row & 7)) << 3);
      gload16(A + (size_t)(row0 + row) * K + gcol, &As[b][row * 64 + blk * 8]);
    }
#pragma unroll
    for (int j = 0; j < 2; ++j) {
      const int idx = j * 512 + tid;
      const int row = idx >> 3, blk = idx & 7;
      const int gcol = k0 + ((blk ^ (row & 7)) << 3);
      gload16(Bt + (size_t)(col0 + row) * K + gcol, &Bs[b][row * 64 + blk * 8]);
    }
  };

  f32x4 acc[8][2] = {};

  stage(0);
  for (int t = 0; t < NT; ++t) {
    const int b = t & 1;
    if (t + 1 < NT) {
      stage(t + 1);
      asm volatile("s_waitcnt vmcnt(6)" ::: "memory");
    } else {
      asm volatile("s_waitcnt vmcnt(0)" ::: "memory");
    }
    __builtin_amdgcn_s_barrier();

    bf16x8 bb[2][2];
#pragma unroll
    for (int n = 0; n < 2; ++n) {
      const int row = wn * 32 + n * 16 + lr;
#pragma unroll
      for (int ch = 0; ch < 2; ++ch) {
        const int blk = (ch * 4 + lk) ^ (row & 7);
        bb[n][ch] = *(const bf16x8*)&Bs[b][row * 64 + blk * 8];
      }
    }
#pragma unroll
    for (int qm = 0; qm < 2; ++qm) {
      bf16x8 a[4][2];
#pragma unroll
      for (int j = 0; j < 4; ++j) {
        const int row = wm * 128 + (qm * 4 + j) * 16 + lr;
#pragma unroll
        for (int ch = 0; ch < 2; ++ch) {
          const int blk = (ch * 4 + lk) ^ (row & 7);
          a[j][ch] = *(const bf16x8*)&As[b][row * 64 + blk * 8];
        }
      }
      __builtin_amdgcn_s_setprio(1);
#pragma unroll
      for (int j = 0; j < 4; ++j)
#pragma unroll
        for (int n = 0; n < 2; ++n)
#pragma unroll
          for (int ch = 0; ch < 2; ++ch)
            acc[qm * 4 + j][n] = __builtin_amdgcn_mfma_f32_16x16x32_bf16(
                a[j][ch], bb[n][ch], acc[qm * 4 + j][n], 0, 0, 0);
      __builtin_amdgcn_s_setprio(0);
    }
    __builtin_amdgcn_s_barrier();
  }

  const int crow0 = row0 + wm * 128 + lk * 4;
  const int ccol0 = col0 + wn * 32 + lr;
#pragma unroll
  for (int mf = 0; mf < 8; ++mf)
#pragma unroll
    for (int nf = 0; nf < 2; ++nf)
#pragma unroll
      for (int r = 0; r < 4; ++r)
        C[(size_t)(crow0 + mf * 16 + r) * N + ccol0 + nf * 16] = acc[mf][nf][r];
}

// ---------------------------------------------------------------------------
// Fused RoPE + latent projection (MFMA), bf16 input, all three tensors in
// one dispatch. grid = (kS/64, 48). Branches block-uniform.
// ---------------------------------------------------------------------------
__global__ __launch_bounds__(256) void rope_latent_all(
    const short* __restrict__ qb, const short* __restrict__ kb,
    const short* __restrict__ vb, const short* __restrict__ WqlT,
    const short* __restrict__ WklT, const short* __restrict__ WvlT,
    const float* __restrict__ tbl, short* __restrict__ q_l,
    short* __restrict__ k_l, short* __restrict__ v_lT) {
  __shared__ short Tw[4][1280];
  const int yz = blockIdx.y;
  const short* in; const short* WT; short* out; int nh; bool ROPE, TR;
  int bh;
  if (yz < 32)      { in = qb; WT = WqlT; out = q_l;  nh = kH;   ROPE = true;  TR = false; bh = yz; }
  else if (yz < 40) { in = kb; WT = WklT; out = k_l;  nh = kHKV; ROPE = true;  TR = false; bh = yz - 32; }
  else              { in = vb; WT = WvlT; out = v_lT; nh = kHKV; ROPE = false; TR = true;  bh = yz - 40; }

  const int tid = threadIdx.x;
  const int lane = tid & 63;
  const int w = tid >> 6;
  const int lr = lane & 15;
  const int lk = lane >> 4;
  const int b = bh / nh, h = bh % nh;
  const int s0 = blockIdx.x * 64;
  const int srow = s0 + w * 16 + lr;
  const int tok = b * kS + srow;

  const short* ip = in + ((size_t)tok * nh + h) * kD + lk * 8;
  bf16x8 raw[4];
#pragma unroll
  for (int ch = 0; ch < 4; ++ch) raw[ch] = *(const bf16x8*)(ip + ch * 32);

  bf16x8 af[4];
  if (ROPE) {
    float a[4][8];
#pragma unroll
    for (int ch = 0; ch < 4; ++ch)
#pragma unroll
      for (int i = 0; i < 8; ++i) a[ch][i] = bf2f(raw[ch][i]);
    const float* tb = tbl + (size_t)tok * 128;
    float c[2][8], sn[2][8];
#pragma unroll
    for (int g = 0; g < 2; ++g) {
      const float4 cA = *(const float4*)(tb + g * 32 + lk * 8);
      const float4 cB = *(const float4*)(tb + g * 32 + lk * 8 + 4);
      const float4 sA = *(const float4*)(tb + 64 + g * 32 + lk * 8);
      const float4 sB = *(const float4*)(tb + 64 + g * 32 + lk * 8 + 4);
      c[g][0] = cA.x; c[g][1] = cA.y; c[g][2] = cA.z; c[g][3] = cA.w;
      c[g][4] = cB.x; c[g][5] = cB.y; c[g][6] = cB.z; c[g][7] = cB.w;
      sn[g][0] = sA.x; sn[g][1] = sA.y; sn[g][2] = sA.z; sn[g][3] = sA.w;
      sn[g][4] = sB.x; sn[g][5] = sB.y; sn[g][6] = sB.z; sn[g][7] = sB.w;
    }
    float o[4][8];
#pragma unroll
    for (int g = 0; g < 2; ++g)
#pragma unroll
      for (int i = 0; i < 8; ++i) {
        o[g][i]     = a[g][i]     * c[g][i] - a[g + 2][i] * sn[g][i];
        o[g + 2][i] = a[g + 2][i] * c[g][i] + a[g][i]     * sn[g][i];
      }
#pragma unroll
    for (int ch = 0; ch < 4; ++ch)
#pragma unroll
      for (int i = 0; i < 8; ++i) af[ch][i] = f2bf(o[ch][i]);
  } else {
#pragma unroll
    for (int ch = 0; ch < 4; ++ch) af[ch] = raw[ch];
  }

  f32x4 acc[4] = {};
#pragma unroll
  for (int cb = 0; cb < 4; ++cb) {
#pragma unroll
    for (int ch = 0; ch < 4; ++ch) {
      const bf16x8 bfrag =
          *(const bf16x8*)&WT[(size_t)(cb * 16 + lr) * kD + ch * 32 + lk * 8];
      acc[cb] = __builtin_amdgcn_mfma_f32_16x16x32_bf16(af[ch], bfrag,
                                                        acc[cb], 0, 0, 0);
    }
  }

  short* T = Tw[w];
  if (!TR) {
#pragma unroll
    for (int cb = 0; cb < 4; ++cb)
#pragma unroll
      for (int r = 0; r < 4; ++r)
        T[(lk * 4 + r) * 72 + cb * 16 + lr] = f2bf(acc[cb][r]);
    asm volatile("s_waitcnt lgkmcnt(0)" ::: "memory");
#pragma unroll
    for (int it = 0; it < 2; ++it) {
      const int idx = it * 64 + lane;
      const int row = idx >> 3, c8 = (idx & 7) << 3;
      *(bf16x8*)&out[((size_t)bh * kS + s0 + w * 16 + row) * kL + c8] =
          *(const bf16x8*)&T[row * 72 + c8];
    }
  } else {
#pragma unroll
    for (int cb = 0; cb < 4; ++cb)
#pragma unroll
      for (int r = 0; r < 4; ++r)
        T[(cb * 16 + lr) * 20 + lk * 4 + r] = f2bf(acc[cb][r]);
    asm volatile("s_waitcnt lgkmcnt(0)" ::: "memory");
    const size_t orow = ((size_t)bh * kL + lane) * kS + s0 + w * 16;
#pragma unroll
    for (int c = 0; c < 4; ++c)
      *(short4*)&out[orow + c * 4] = *(const short4*)&T[lane * 20 + c * 4];
  }
}

// ---------------------------------------------------------------------------
// MFMA flash attention, causal, bf16 in/out (fp32 accumulate).
// Swapped QK^T (q lane-local), in-register P via shuffles, T13 defer-max.
// 128-KEY double-buffered K/V tiles: two 64-key compute subtiles per staged
// tile -> ONE barrier per 128 keys. (R13 version — R14 pairing reverted.)
// ---------------------------------------------------------------------------
__global__ __launch_bounds__(512) void flash_attn_mfma(
    const short* __restrict__ ql, const short* __restrict__ kl,
    const short* __restrict__ vlT, short* __restrict__ attn_out) {
  constexpr int LDK = 72;                      // K rows: 64 lat + 8 pad
  constexpr int LDV = 136;                     // V rows: 128 keys + 8 pad
  __shared__ short Kt[2][128 * LDK];
  __shared__ short Vt[2][64 * LDV];            // row = latent l, col = key

  const int tid = threadIdx.x;
  const int lane = tid & 63;
  const int w = tid >> 6;
  const int lr = lane & 15;
  const int lk = lane >> 4;
  const int bid = blockIdx.y;
  const int bx = (bid < 8) ? (2 * bid) : (31 - 2 * bid);   // load-balance remap
  const int q0 = bx * 128;
  const int bh = blockIdx.x;
  const int b = bh >> 4, h = bh & 15;
  const int hk = h >> 2;
  const int wrow = q0 + w * 16;

  const short* qrow = ql + ((size_t)bh * kS + wrow + lr) * kL;
  bf16x8 qf[2];
  qf[0] = *(const bf16x8*)(qrow + lk * 8);
  qf[1] = *(const bf16x8*)(qrow + 32 + lk * 8);

  f32x4 Of[4] = {};                            // O^T[l=lb*16+lk*4+r][q=lr]
  float m = -3.0e38f, l = 0.f;

  const short* kgp = kl + (size_t)(b * kHKV + hk) * kS * kL;
  const short* vgp = vlT + (size_t)(b * kHKV + hk) * kL * kS;
  const int ntiles = bx + 1;                   // 128-key tiles

  const int kr0 = tid >> 3,          kc0 = (tid & 7) << 3;
  const int kr1 = (512 + tid) >> 3,  kc1 = (tid & 7) << 3;
  const int vr0 = tid >> 4,          vc0 = (tid & 15) << 3;
  const int vr1 = (512 + tid) >> 4,  vc1 = (tid & 15) << 3;

  // prologue: stage tile 0 (keys 0..127) into buffer 0
  *(bf16x8*)&Kt[0][kr0 * LDK + kc0] = *(const bf16x8*)(kgp + (size_t)kr0 * kL + kc0);
  *(bf16x8*)&Kt[0][kr1 * LDK + kc1] = *(const bf16x8*)(kgp + (size_t)kr1 * kL + kc1);
  *(bf16x8*)&Vt[0][vr0 * LDV + vc0] = *(const bf16x8*)(vgp + (size_t)vr0 * kS + vc0);
  *(bf16x8*)&Vt[0][vr1 * LDV + vc1] = *(const bf16x8*)(vgp + (size_t)vr1 * kS + vc1);
  __syncthreads();

  const int sl0 = lr + ((lane & 16) << 1);     // lr + 32*(lk&1)
  const bool hisel = (lk >> 1) != 0;

  int cur = 0;
  for (int t = 0; t < ntiles; ++t) {
    const int j0 = t * 128;
    const bool pre = (t + 1 < ntiles);
    bf16x8 krn0, krn1, vrn0, vrn1;
    if (pre) {                                 // issue next-tile loads EARLY
      const int jn = j0 + 128;
      krn0 = *(const bf16x8*)(kgp + (size_t)(jn + kr0) * kL + kc0);
      krn1 = *(const bf16x8*)(kgp + (size_t)(jn + kr1) * kL + kc1);
      vrn0 = *(const bf16x8*)(vgp + (size_t)vr0 * kS + jn + vc0);
      vrn1 = *(const bf16x8*)(vgp + (size_t)vr1 * kS + jn + vc1);
    }

    const short* Kc = &Kt[cur][0];
    const short* Vc = &Vt[cur][0];
#pragma unroll
    for (int sub = 0; sub < 2; ++sub) {
      const int js = j0 + sub * 64;
      if (js > wrow) continue;                 // wave-uniform causal skip

      // S^T = K @ Q : Sf[cb][r] = S[key=js+cb*16+lk*4+r][q=wrow+lr]
      f32x4 Sf[4];
      __builtin_amdgcn_s_setprio(1);
#pragma unroll
      for (int cb = 0; cb < 4; ++cb) {
        f32x4 acc = {};
#pragma unroll
        for (int ch = 0; ch < 2; ++ch) {
          const bf16x8 kf = *(const bf16x8*)
              &Kc[(sub * 64 + cb * 16 + lr) * LDK + ch * 32 + lk * 8];
          acc = __builtin_amdgcn_mfma_f32_16x16x32_bf16(kf, qf[ch], acc, 0, 0, 0);
        }
        Sf[cb] = acc;
      }
      __builtin_amdgcn_s_setprio(0);

      // causal mask (diagonal subtile only) + local max
      float mt = -3.0e38f;
      if (js + 63 > wrow) {
#pragma unroll
        for (int cb = 0; cb < 4; ++cb)
#pragma unroll
          for (int r = 0; r < 4; ++r) {
            float s = Sf[cb][r];
            if ((js + cb * 16 + lk * 4 + r) > (wrow + lr)) s = -3.0e38f;
            Sf[cb][r] = s;
            mt = fmaxf(mt, s);
          }
      } else {
#pragma unroll
        for (int cb = 0; cb < 4; ++cb)
#pragma unroll
          for (int r = 0; r < 4; ++r) mt = fmaxf(mt, Sf[cb][r]);
      }
      mt = fmaxf(mt, __shfl_xor(mt, 16));
      mt = fmaxf(mt, __shfl_xor(mt, 32));

      // T13 defer-max
      const bool resc = __any((int)(mt > m + 8.f));
      if (resc) {
        const float mnew = fmaxf(m, mt);
        const float corr = __expf(m - mnew);
        m = mnew;
        l *= corr;
#pragma unroll
        for (int lb = 0; lb < 4; ++lb)
#pragma unroll
          for (int r = 0; r < 4; ++r) Of[lb][r] *= corr;
      }

      // P = exp(S - m), packed bf16 pairs per cb
      unsigned pk[4][2];
#pragma unroll
      for (int cb = 0; cb < 4; ++cb) {
        const float p0 = __expf(Sf[cb][0] - m);
        const float p1 = __expf(Sf[cb][1] - m);
        const float p2 = __expf(Sf[cb][2] - m);
        const float p3 = __expf(Sf[cb][3] - m);
        l += (p0 + p1) + (p2 + p3);
        pk[cb][0] = cvt_pk_bf16(p0, p1);
        pk[cb][1] = cvt_pk_bf16(p2, p3);
      }

      // PV: per ch, build P^T B-fragment via in-register shuffles, then MFMA
#pragma unroll
      for (int ch = 0; ch < 2; ++ch) {
        const unsigned lo00 = __shfl(pk[2 * ch][0], sl0);
        const unsigned lo01 = __shfl(pk[2 * ch][1], sl0);
        const unsigned lo10 = __shfl(pk[2 * ch][0], sl0 + 16);
        const unsigned lo11 = __shfl(pk[2 * ch][1], sl0 + 16);
        const unsigned hi00 = __shfl(pk[2 * ch + 1][0], sl0);
        const unsigned hi01 = __shfl(pk[2 * ch + 1][1], sl0);
        const unsigned hi10 = __shfl(pk[2 * ch + 1][0], sl0 + 16);
        const unsigned hi11 = __shfl(pk[2 * ch + 1][1], sl0 + 16);
        union { unsigned u[4]; bf16x8 v; } pf;
        pf.u[0] = hisel ? hi00 : lo00;
        pf.u[1] = hisel ? hi01 : lo01;
        pf.u[2] = hisel ? hi10 : lo10;
        pf.u[3] = hisel ? hi11 : lo11;
        __builtin_amdgcn_s_setprio(1);
#pragma unroll
        for (int lb = 0; lb < 4; ++lb) {
          const bf16x8 vf = *(const bf16x8*)
              &Vc[(lb * 16 + lr) * LDV + sub * 64 + ch * 32 + lk * 8];
          Of[lb] = __builtin_amdgcn_mfma_f32_16x16x32_bf16(vf, pf.v, Of[lb], 0, 0, 0);
        }
        __builtin_amdgcn_s_setprio(0);
      }
    }

    if (pre) {                                 // write-late into other buffer
      *(bf16x8*)&Kt[cur ^ 1][kr0 * LDK + kc0] = krn0;
      *(bf16x8*)&Kt[cur ^ 1][kr1 * LDK + kc1] = krn1;
      *(bf16x8*)&Vt[cur ^ 1][vr0 * LDV + vc0] = vrn0;
      *(bf16x8*)&Vt[cur ^ 1][vr1 * LDV + vc1] = vrn1;
    }
    __syncthreads();                           // ONE barrier per 128 keys
    cur ^= 1;
  }

  // final lsum reduce (over lk groups) + O^T write: 4x short4 per lane
  l += __shfl_xor(l, 16);
  l += __shfl_xor(l, 32);
  const float inv = 1.f / l;
  const size_t rowoff =
      (size_t)(b * kS + wrow + lr) * (kH * kL) + h * kL + lk * 4;
#pragma unroll
  for (int lb = 0; lb < 4; ++lb) {
    const short4 s4 = make_short4(f2bf(Of[lb][0] * inv), f2bf(Of[lb][1] * inv),
                                  f2bf(Of[lb][2] * inv), f2bf(Of[lb][3] * inv));
    *(short4*)&attn_out[rowoff + lb * 16] = s4;
  }
}

// ---------------------------------------------------------------------------
extern "C" void kernel_launch(void* const* d_in, const int* in_sizes, int n_in,
                              void* d_out, int out_size, void* d_ws, size_t ws_size,
                              hipStream_t stream) {
  const float* x    = (const float*)d_in[0];
  const int*   pos  = (const int*)d_in[1];
  const float* Wq   = (const float*)d_in[3];
  const float* Wk   = (const float*)d_in[4];
  const float* Wv   = (const float*)d_in[5];
  const float* Wql  = (const float*)d_in[6];
  const float* Wkl  = (const float*)d_in[7];
  const float* Wvl  = (const float*)d_in[8];
  const float* Wo   = (const float*)d_in[9];
  float* out = (float*)d_out;

  // Workspace carve (q_buf bf16 reuses d_out: 16 MB of its 32 MB)
  char* p = (char*)d_ws;
  short* x_bf  = (short*)p; p += (size_t)kTok * kHID * 2;        // 16 MB
  short* Wqkv  = (short*)p; p += (size_t)kNQKV * kHID * 2;       // 12.6 MB
  short* WoT   = (short*)p; p += (size_t)kHID * (kH * kL) * 2;   // 4 MB
  short* WqlT  = (short*)p; p += (size_t)kL * kD * 2;            // 16 KB
  short* WklT  = (short*)p; p += (size_t)kL * kD * 2;
  short* WvlT  = (short*)p; p += (size_t)kL * kD * 2;
  float* tbl   = (float*)p; p += (size_t)kTok * 128 * 4;         // 2 MB
  short* k_buf = (short*)p; p += (size_t)kTok * kHKV * kD * 2;   // 4 MB
  short* v_buf = (short*)p; p += (size_t)kTok * kHKV * kD * 2;   // 4 MB
  short* q_l   = (short*)p; p += (size_t)kB * kH * kS * kL * 2;  // 8 MB
  short* k_l   = (short*)p; p += (size_t)kB * kHKV * kS * kL * 2;
  short* v_lT  = (short*)p; p += (size_t)kB * kHKV * kS * kL * 2;
  short* attn  = (short*)p;                                      // 8 MB
  short* q_buf = (short*)d_out;   // bf16 scratch until final GEMM

  // 0) fused prep — one dispatch (cvt + trig + 3 weight transposes)
  prep_all<<<7174, 256, 0, stream>>>(x, pos, Wq, Wk, Wv, Wo, Wql, Wkl, Wvl,
                                     x_bf, tbl, Wqkv, WoT, WqlT, WklT, WvlT);

  // 1) Fused QKV projection — 256² 2-deep counted-vmcnt, register-blocked
  gemm_qkv8<<<dim3(kNQKV / 256, kTok / 256), 512, 0, stream>>>(
      x_bf, Wqkv, q_buf, k_buf, v_buf, kHID);

  // 2) Fused RoPE + latent projections — single dispatch
  rope_latent_all<<<dim3(kS / 64, 48), 256, 0, stream>>>(
      q_buf, k_buf, v_buf, WqlT, WklT, WvlT, tbl, q_l, k_l, v_lT);

  // 3) MFMA flash attention (swapped QK^T, 128-key dbuf tiles)
  flash_attn_mfma<<<dim3(kB * kH, kS / 128), 512, 0, stream>>>(
      q_l, k_l, v_lT, attn);

  // 4) Output GEMM — 256x128 2-deep, 256 blocks = 1/CU, fp32 out
  gemm_out8<<<dim3(kHID / 128, kTok / 256), 512, 0, stream>>>(
      attn, WoT, out, kTok, kHID, kH * kL);
}